// Round 14
// baseline (11262.902 us; speedup 1.0000x reference)
//
#include <hip/hip_runtime.h>
#include <stdint.h>
#include <math.h>

// Problem constants (fixed by setup_inputs)
#define B_     128
#define S_     128
#define V_     8000
#define E_     512
#define H_     2048
#define H4_    8192
#define GIVEN_ 64

typedef __bf16 bf16x8 __attribute__((ext_vector_type(8)));
typedef float  f32x16 __attribute__((ext_vector_type(16)));
typedef short  short8 __attribute__((ext_vector_type(8)));
typedef unsigned long long u64;

// ---------------------------------------------------------------------------
// Threefry-2x32 (20 rounds) — exact JAX semantics (verified passing r3-r13)
// ---------------------------------------------------------------------------
__device__ __forceinline__ uint32_t rotl32(uint32_t v, int d) {
  return (v << d) | (v >> (32 - d));
}

__device__ __forceinline__ void threefry2x32(uint32_t k0, uint32_t k1,
                                             uint32_t x0, uint32_t x1,
                                             uint32_t& o0, uint32_t& o1) {
  uint32_t k2 = k0 ^ k1 ^ 0x1BD11BDAu;
  x0 += k0; x1 += k1;
#define TF_RND(R) { x0 += x1; x1 = rotl32(x1, (R)); x1 ^= x0; }
  TF_RND(13) TF_RND(15) TF_RND(26) TF_RND(6)
  x0 += k1; x1 += k2 + 1u;
  TF_RND(17) TF_RND(29) TF_RND(16) TF_RND(24)
  x0 += k2; x1 += k0 + 2u;
  TF_RND(13) TF_RND(15) TF_RND(26) TF_RND(6)
  x0 += k0; x1 += k1 + 3u;
  TF_RND(17) TF_RND(29) TF_RND(16) TF_RND(24)
  x0 += k1; x1 += k2 + 4u;
  TF_RND(13) TF_RND(15) TF_RND(26) TF_RND(6)
  x0 += k2; x1 += k0 + 5u;
#undef TF_RND
  o0 = x0; o1 = x1;
}

__global__ void keys_kernel(uint32_t* __restrict__ keys) {
  int t = threadIdx.x;  // 0..63
  uint32_t o0, o1;
  threefry2x32(0u, 1u, 0u, (uint32_t)t, o0, o1);
  keys[2 * t]     = o0;
  keys[2 * t + 1] = o1;
}

__global__ void copy_prefix(const int* __restrict__ x, int* __restrict__ out) {
  int idx = blockIdx.x * blockDim.x + threadIdx.x;
  int b = idx >> 6;
  int s = idx & 63;
  out[b * S_ + s] = x[b * S_ + s];
}

// split f32 -> hi/lo bf16 (truncation; identical math to passing rounds)
__device__ __forceinline__ void split2(float x, uint16_t& hi, uint16_t& lo) {
  uint32_t xb = __float_as_uint(x);
  hi = (uint16_t)(xb >> 16);
  float l = x - __uint_as_float(xb & 0xFFFF0000u);
  lo = (uint16_t)(__float_as_uint(l) >> 16);
}

__device__ __forceinline__ void splitpack(float4 a, float4 b,
                                          bf16x8& hi, bf16x8& lo) {
  float e[8] = {a.x, a.y, a.z, a.w, b.x, b.y, b.z, b.w};
  short8 h, l;
#pragma unroll
  for (int j = 0; j < 8; ++j) {
    uint16_t h16, l16;
    split2(e[j], h16, l16);
    h[j] = (short)h16;
    l[j] = (short)l16;
  }
  hi = __builtin_bit_cast(bf16x8, h);
  lo = __builtin_bit_cast(bf16x8, l);
}

// unpack packed-3B weight frag: hi bf16x8 (direct) + 8 mid-bytes -> lo bf16x8
__device__ __forceinline__ void unpack3(short8 hv, uint2 m, bf16x8& bh, bf16x8& bl) {
  short8 lv;
#pragma unroll
  for (int j = 0; j < 8; ++j) {
    uint32_t hbits = ((uint32_t)(uint16_t)hv[j]) << 16;
    uint32_t mbyte = ((j < 4 ? (m.x >> (8 * j)) : (m.y >> (8 * (j - 4)))) & 0xFFu);
    float xf = __uint_as_float(hbits | (mbyte << 8));
    float lf = xf - __uint_as_float(hbits);
    lv[j] = (short)(__float_as_uint(lf) >> 16);
  }
  bh = __builtin_bit_cast(bf16x8, hv);
  bl = __builtin_bit_cast(bf16x8, lv);
}

// ---------------------------------------------------------------------------
// Panel packer (r13 verbatim): W (N x K f32) -> PH/PM in MFMA fragment order.
// ---------------------------------------------------------------------------
__global__ void pack3_panel(
    const float* __restrict__ W, uint16_t* __restrict__ PH,
    uint8_t* __restrict__ PM, int K, int nks, int gateRe)
{
  const int bid = blockIdx.x;
  const int jb = bid / nks, ks = bid - jb * nks;
  const int t = threadIdx.x;     // 0..63
  const int lrow = t & 31, lgrp = t >> 5;
  const int wrow = gateRe ? ((lrow >> 3) * H_ + jb * 8 + (lrow & 7))
                          : (jb * 32 + lrow);
  const float* src = W + (size_t)wrow * K + ks * 16 + lgrp * 8;
  float4 a = ((const float4*)src)[0];
  float4 b = ((const float4*)src)[1];
  float e[8] = {a.x, a.y, a.z, a.w, b.x, b.y, b.z, b.w};
  short8 h;
  uint32_t mlo = 0, mhi = 0;
#pragma unroll
  for (int j = 0; j < 8; ++j) {
    uint32_t xb = __float_as_uint(e[j]);
    h[j] = (short)(xb >> 16);
    uint32_t mb = (xb >> 8) & 0xFFu;
    if (j < 4) mlo |= mb << (8 * j);
    else       mhi |= mb << (8 * (j - 4));
  }
  const size_t bi = ((size_t)bid * 64 + t) * 8;
  *(short8*)&PH[bi] = h;
  *(uint2*)&PM[bi] = make_uint2(mlo, mhi);
}

#define MFMA_(a, b, c) __builtin_amdgcn_mfma_f32_32x32x16_bf16(a, b, c, 0, 0, 0)

// ===========================================================================
// GEMM phase (r13 verbatim structure). GMODE: 0 = staged-h A, 1 = emb gather
// via ridx, 2 = emb gather via direct token values.
// ===========================================================================
template<int GMODE>
__device__ __forceinline__ void run_phase_p(
    f32x16 (&acc)[4],
    const float* __restrict__ aF,
    const uint16_t* __restrict__ aHi, const uint16_t* __restrict__ aLo,
    const int* __restrict__ ridx, int rstride,
    int tk0, int tk1, int tk2, int tk3,
    const uint16_t* __restrict__ PH, const uint8_t* __restrict__ PM,
    int K, int jb, int w, int lane, int lrow, int lgrp)
{
  constexpr bool G = (GMODE != 0);
  const int nFS = K >> 7;               // k16-steps per wave (4 or 16)
  const size_t bbase = (size_t)jb * (K >> 4);

  size_t aoff0, aoff1, aoff2, aoff3;
  if (GMODE == 1) {
    aoff0 = (size_t)ridx[(size_t)(lrow)      * rstride] * E_ + lgrp * 8;
    aoff1 = (size_t)ridx[(size_t)(32 + lrow) * rstride] * E_ + lgrp * 8;
    aoff2 = (size_t)ridx[(size_t)(64 + lrow) * rstride] * E_ + lgrp * 8;
    aoff3 = (size_t)ridx[(size_t)(96 + lrow) * rstride] * E_ + lgrp * 8;
  } else if (GMODE == 2) {
    aoff0 = (size_t)tk0 * E_ + lgrp * 8;
    aoff1 = (size_t)tk1 * E_ + lgrp * 8;
    aoff2 = (size_t)tk2 * E_ + lgrp * 8;
    aoff3 = (size_t)tk3 * E_ + lgrp * 8;
  } else {
    aoff0 = (size_t)lgrp * 256 + (size_t)lrow * 8;
    aoff1 = aoff0 + 512;
    aoff2 = aoff0 + 1024;
    aoff3 = aoff0 + 1536;
  }

  short8 bH[2]; uint2 bM[2];
  float4 gR0[2][2], gR1[2][2], gR2[2][2], gR3[2][2];
  bf16x8 sh0[2], sh1[2], sh2[2], sh3[2], sl0[2], sl1[2], sl2[2], sl3[2];

#define LOADFS(BUF, KS)                                                      \
  {                                                                          \
    const size_t bi = ((bbase + (size_t)(KS)) * 64 + (size_t)lane) * 8;      \
    bH[BUF] = *(const short8*)(PH + bi);                                     \
    bM[BUF] = *(const uint2*)(PM + bi);                                      \
    if (G) {                                                                 \
      const float* a0 = aF + aoff0 + (size_t)(KS) * 16;                      \
      const float* a1 = aF + aoff1 + (size_t)(KS) * 16;                      \
      const float* a2 = aF + aoff2 + (size_t)(KS) * 16;                      \
      const float* a3 = aF + aoff3 + (size_t)(KS) * 16;                      \
      gR0[BUF][0] = ((const float4*)a0)[0]; gR0[BUF][1] = ((const float4*)a0)[1]; \
      gR1[BUF][0] = ((const float4*)a1)[0]; gR1[BUF][1] = ((const float4*)a1)[1]; \
      gR2[BUF][0] = ((const float4*)a2)[0]; gR2[BUF][1] = ((const float4*)a2)[1]; \
      gR3[BUF][0] = ((const float4*)a3)[0]; gR3[BUF][1] = ((const float4*)a3)[1]; \
    } else {                                                                 \
      size_t o0 = aoff0 + (size_t)(KS) * 2048;                               \
      size_t o1 = aoff1 + (size_t)(KS) * 2048;                               \
      size_t o2 = aoff2 + (size_t)(KS) * 2048;                               \
      size_t o3 = aoff3 + (size_t)(KS) * 2048;                               \
      sh0[BUF] = *(const bf16x8*)(aHi + o0); sl0[BUF] = *(const bf16x8*)(aLo + o0); \
      sh1[BUF] = *(const bf16x8*)(aHi + o1); sl1[BUF] = *(const bf16x8*)(aLo + o1); \
      sh2[BUF] = *(const bf16x8*)(aHi + o2); sl2[BUF] = *(const bf16x8*)(aLo + o2); \
      sh3[BUF] = *(const bf16x8*)(aHi + o3); sl3[BUF] = *(const bf16x8*)(aLo + o3); \
    }                                                                        \
  }

#define COMPFS(BUF)                                                          \
  {                                                                          \
    bf16x8 bh, bl;                                                           \
    unpack3(bH[BUF], bM[BUF], bh, bl);                                       \
    bf16x8 ah, al;                                                           \
    if (G) splitpack(gR0[BUF][0], gR0[BUF][1], ah, al);                      \
    else { ah = sh0[BUF]; al = sl0[BUF]; }                                   \
    acc[0] = MFMA_(ah, bh, acc[0]);                                          \
    acc[0] = MFMA_(ah, bl, acc[0]);                                          \
    acc[0] = MFMA_(al, bh, acc[0]);                                          \
    if (G) splitpack(gR1[BUF][0], gR1[BUF][1], ah, al);                      \
    else { ah = sh1[BUF]; al = sl1[BUF]; }                                   \
    acc[1] = MFMA_(ah, bh, acc[1]);                                          \
    acc[1] = MFMA_(ah, bl, acc[1]);                                          \
    acc[1] = MFMA_(al, bh, acc[1]);                                          \
    if (G) splitpack(gR2[BUF][0], gR2[BUF][1], ah, al);                      \
    else { ah = sh2[BUF]; al = sl2[BUF]; }                                   \
    acc[2] = MFMA_(ah, bh, acc[2]);                                          \
    acc[2] = MFMA_(ah, bl, acc[2]);                                          \
    acc[2] = MFMA_(al, bh, acc[2]);                                          \
    if (G) splitpack(gR3[BUF][0], gR3[BUF][1], ah, al);                      \
    else { ah = sh3[BUF]; al = sl3[BUF]; }                                   \
    acc[3] = MFMA_(ah, bh, acc[3]);                                          \
    acc[3] = MFMA_(ah, bl, acc[3]);                                          \
    acc[3] = MFMA_(al, bh, acc[3]);                                          \
  }

  int ks = w;
  LOADFS(0, ks); ks += 8;
  int rem = nFS;              // even: 4 or 16
  while (rem >= 2) {
    LOADFS(1, ks); ks += 8;
    COMPFS(0);
    if (rem > 2) { LOADFS(0, ks); ks += 8; }
    COMPFS(1);
    rem -= 2;
  }
#undef LOADFS
#undef COMPFS
}

// ---------------------------------------------------------------------------
// Shared reduce + epilogue helpers (r13 verbatim logic)
// ---------------------------------------------------------------------------
__device__ __forceinline__ void reduce_waves(float (*red)[4096],
                                             f32x16 (&acc)[4], int tid) {
  const int w = tid >> 6, lane = tid & 63;
  const int lrow = lane & 31, lgrp = lane >> 5;
  const int wl = w & 3;
  if (w < 4) {
#pragma unroll
    for (int mf = 0; mf < 4; ++mf)
#pragma unroll
      for (int r = 0; r < 16; ++r) {
        const int row = mf * 32 + (r & 3) + 8 * (r >> 2) + 4 * lgrp;
        red[wl][row * 32 + (lrow ^ (row & 31))] = acc[mf][r];
      }
  }
  __syncthreads();
  if (w >= 4) {
#pragma unroll
    for (int mf = 0; mf < 4; ++mf)
#pragma unroll
      for (int r = 0; r < 16; ++r) {
        const int row = mf * 32 + (r & 3) + 8 * (r >> 2) + 4 * lgrp;
        red[wl][row * 32 + (lrow ^ (row & 31))] += acc[mf][r];
      }
  }
  __syncthreads();
}

__device__ __forceinline__ void gates_epilogue(
    float (*red)[4096], int jb, int tid,
    const float* __restrict__ bih, const float* __restrict__ bhh,
    const float* __restrict__ G0,
    float* __restrict__ cS,
    uint16_t* __restrict__ hOutHi, uint16_t* __restrict__ hOutLo)
{
  const int b  = tid & 127;
  const int uh = (tid >> 7) * 2;   // 0,2,4,6
#pragma unroll
  for (int q = 0; q < 2; ++q) {
    const int u = uh + q;
    float gs[4];
#pragma unroll
    for (int g = 0; g < 4; ++g) {
      const int cs = (g * 8 + u) ^ (b & 31);
      gs[g] = ((red[0][b * 32 + cs] + red[1][b * 32 + cs])
               + red[2][b * 32 + cs]) + red[3][b * 32 + cs];
      if (G0) gs[g] += G0[((size_t)b * 256 + jb) * 32 + g * 8 + u];
    }
    const int n = jb * 8 + u;
    float gi = gs[0] + bih[n]          + bhh[n];
    float gf = gs[1] + bih[H_ + n]     + bhh[H_ + n];
    float gg = gs[2] + bih[2 * H_ + n] + bhh[2 * H_ + n];
    float go = gs[3] + bih[3 * H_ + n] + bhh[3 * H_ + n];
    float si = 1.f / (1.f + expf(-gi));
    float sf = 1.f / (1.f + expf(-gf));
    float so = 1.f / (1.f + expf(-go));
    const size_t ci = (size_t)b * H_ + n;
    float cv = sf * cS[ci] + si * tanhf(gg);
    cS[ci] = cv;
    float hv = so * tanhf(cv);
    uint16_t hh, hl;
    split2(hv, hh, hl);
    const size_t hoff = (size_t)((n >> 4) * 4 + (b >> 5)) * 512
                      + (size_t)((n >> 3) & 1) * 256
                      + (size_t)(b & 31) * 8 + (size_t)(n & 7);
    hOutHi[hoff] = hh;
    hOutLo[hoff] = hl;
  }
}

// ---------------------------------------------------------------------------
// Layer duty parameter bundle + duty body
// ---------------------------------------------------------------------------
struct LayerArgs {
  const float* aF; const int* ridx; int rstride;
  const uint16_t* a1Hi; const uint16_t* a1Lo;
  const uint16_t* PH1; const uint8_t* PM1; int K1;
  const uint16_t* a2Hi; const uint16_t* a2Lo;
  const uint16_t* PH2; const uint8_t* PM2; int K2;
  const float* bih; const float* bhh; float* cS;
  uint16_t* hOutHi; uint16_t* hOutLo;
};

template<int GMODE1>
__device__ __forceinline__ void do_lstm_duty(const LayerArgs& A,
                                             float (*red)[4096],
                                             int jb, int tid)
{
  const int w = tid >> 6, lane = tid & 63;
  const int lrow = lane & 31, lgrp = lane >> 5;
  f32x16 acc[4];
#pragma unroll
  for (int mf = 0; mf < 4; ++mf)
#pragma unroll
    for (int r = 0; r < 16; ++r) acc[mf][r] = 0.0f;

  run_phase_p<GMODE1>(acc, A.aF, A.a1Hi, A.a1Lo, A.ridx, A.rstride, 0, 0, 0, 0,
                      A.PH1, A.PM1, A.K1, jb, w, lane, lrow, lgrp);
  if (A.K2 > 0)
    run_phase_p<0>(acc, nullptr, A.a2Hi, A.a2Lo, nullptr, 0, 0, 0, 0, 0,
                   A.PH2, A.PM2, A.K2, jb, w, lane, lrow, lgrp);
  reduce_waves(red, acc, tid);
  gates_epilogue(red, jb, tid, A.bih, A.bhh, nullptr, A.cS, A.hOutHi, A.hOutLo);
}

// ---------------------------------------------------------------------------
// Kernels
// ---------------------------------------------------------------------------
template<int GMODE1>
__global__ __launch_bounds__(512, 2) void lstm_single(LayerArgs A) {
  __shared__ float red[4][4096];
  do_lstm_duty<GMODE1>(A, red, blockIdx.x, threadIdx.x);
}

// TF fused: y=0 -> L1[t-1] (staged), y=1 -> L0[t] (emb gather via x)
__global__ __launch_bounds__(512, 2) void fused_tf(LayerArgs L1A, LayerArgs L0A) {
  __shared__ float red[4][4096];
  if (blockIdx.y == 0) do_lstm_duty<0>(L1A, red, blockIdx.x, threadIdx.x);
  else                 do_lstm_duty<1>(L0A, red, blockIdx.x, threadIdx.x);
}

// Rollout fused: y=0 -> L1[t] full; y=1 -> L0hh partial for step t+1 -> G0
__global__ __launch_bounds__(512, 2) void fused_r(
    LayerArgs L1A,
    const uint16_t* __restrict__ hhHi, const uint16_t* __restrict__ hhLo,
    const uint16_t* __restrict__ PHhh0, const uint8_t* __restrict__ PMhh0,
    float* __restrict__ G0, int doPartial)
{
  __shared__ float red[4][4096];
  const int jb = blockIdx.x, tid = threadIdx.x;
  if (blockIdx.y == 0) {
    do_lstm_duty<0>(L1A, red, jb, tid);
    return;
  }
  if (!doPartial) return;
  const int w = tid >> 6, lane = tid & 63;
  const int lrow = lane & 31, lgrp = lane >> 5;
  f32x16 acc[4];
#pragma unroll
  for (int mf = 0; mf < 4; ++mf)
#pragma unroll
    for (int r = 0; r < 16; ++r) acc[mf][r] = 0.0f;
  run_phase_p<0>(acc, nullptr, hhHi, hhLo, nullptr, 0, 0, 0, 0, 0,
                 PHhh0, PMhh0, H_, jb, w, lane, lrow, lgrp);
  reduce_waves(red, acc, tid);
  const int b = tid & 127, ch = (tid >> 7) * 8;
#pragma unroll
  for (int q = 0; q < 8; ++q) {
    const int col = ch + q;
    const int cs  = col ^ (b & 31);
    float v = ((red[0][b * 32 + cs] + red[1][b * 32 + cs])
               + red[2][b * 32 + cs]) + red[3][b * 32 + cs];
    G0[((size_t)b * 256 + jb) * 32 + col] = v;
  }
}

// sortable-f32 pack: monotonic u32; ties -> lower idx wins via ~idx in low32
__device__ __forceinline__ u64 pack_key(float v, uint32_t gidx) {
  uint32_t fb = __float_as_uint(v);
  fb = (fb & 0x80000000u) ? ~fb : (fb | 0x80000000u);
  return ((u64)fb << 32) | (u64)(0xFFFFFFFFu ^ gidx);
}

// logits + gumbel + per-block argmax partials (plain stores, no atomics)
__global__ __launch_bounds__(512, 2) void logits_pmax(
    const uint16_t* __restrict__ aHi, const uint16_t* __restrict__ aLo,
    const uint16_t* __restrict__ PHlin, const uint8_t* __restrict__ PMlin,
    const float* __restrict__ blin, const uint32_t* __restrict__ keys, int t,
    u64* __restrict__ winPart)
{
  __shared__ float red[4][4096];
  const int jb = blockIdx.x, tid = threadIdx.x;
  const int w = tid >> 6, lane = tid & 63;
  const int lrow = lane & 31, lgrp = lane >> 5;
  f32x16 acc[4];
#pragma unroll
  for (int mf = 0; mf < 4; ++mf)
#pragma unroll
    for (int r = 0; r < 16; ++r) acc[mf][r] = 0.0f;
  run_phase_p<0>(acc, nullptr, aHi, aLo, nullptr, 0, 0, 0, 0, 0,
                 PHlin, PMlin, H_, jb, w, lane, lrow, lgrp);
  reduce_waves(red, acc, tid);

  const int b = tid & 127, ch = (tid >> 7) * 8;
  const uint32_t k0 = keys[2 * t], k1 = keys[2 * t + 1];
  u64 lk = 0;
#pragma unroll
  for (int q = 0; q < 8; ++q) {
    const int col = ch + q;
    const int cs  = col ^ (b & 31);
    float v = ((red[0][b * 32 + cs] + red[1][b * 32 + cs])
               + red[2][b * 32 + cs]) + red[3][b * 32 + cs];
    v += blin[jb * 32 + col];
    const uint32_t gidx = (uint32_t)(jb * 32 + col);
    uint32_t j = (uint32_t)b * (uint32_t)V_ + gidx;
    uint32_t o0, o1;
    threefry2x32(k0, k1, 0u, j, o0, o1);
    uint32_t bits = o0 ^ o1;
    float f = __uint_as_float((bits >> 9) | 0x3f800000u) - 1.0f;
    float u = fmaxf(1.17549435e-38f, f + 1.17549435e-38f);
    float t1 = (float)log((double)u);
    float t2 = -t1;
    float t3 = (float)log((double)t2);
    float val = (-t3) + v;
    u64 key = pack_key(val, gidx);
    if (key > lk) lk = key;
  }
  __syncthreads();   // red reads complete; reuse as u64 scratch
  u64* wsh = (u64*)&red[0][0];
  wsh[b * 4 + (tid >> 7)] = lk;
  __syncthreads();
  if (tid < 128) {
    u64 m = wsh[tid * 4];
#pragma unroll
    for (int i = 1; i < 4; ++i) { u64 k2 = wsh[tid * 4 + i]; if (k2 > m) m = k2; }
    winPart[(size_t)tid * 250 + jb] = m;
  }
}

// finish L0[t+1]: decode tokens from winPart, emb-gather K=512, + G0, gates.
__global__ __launch_bounds__(512, 2) void l0_finish(
    const u64* __restrict__ winPart,
    const float* __restrict__ emb,
    const uint16_t* __restrict__ PHih0, const uint8_t* __restrict__ PMih0,
    const float* __restrict__ G0,
    const float* __restrict__ bih0, const float* __restrict__ bhh0,
    float* __restrict__ c0,
    uint16_t* __restrict__ hOutHi, uint16_t* __restrict__ hOutLo,
    int* __restrict__ out, int outCol)
{
  __shared__ float red[4][4096];
  const int jb = blockIdx.x, tid = threadIdx.x;

  // stage A: token decode (winPart fully written by logits_pmax)
  u64* wsh = (u64*)&red[0][0];                       // 4 KB
  int* tokLds = (int*)((char*)&red[0][0] + 4096);    // 512 B
  {
    const int r = tid >> 2, qq = tid & 3;
    u64 m = 0;
    for (int j = qq; j < 250; j += 4) {
      u64 k2 = winPart[(size_t)r * 250 + j];
      if (k2 > m) m = k2;
    }
    wsh[r * 4 + qq] = m;
  }
  __syncthreads();
  if (tid < 128) {
    u64 m = wsh[tid * 4];
#pragma unroll
    for (int i = 1; i < 4; ++i) { u64 k2 = wsh[tid * 4 + i]; if (k2 > m) m = k2; }
    int tok = (int)(~(uint32_t)(m & 0xFFFFFFFFull));
    tokLds[tid] = tok;
    if (jb == 0) out[tid * S_ + outCol] = tok;
  }
  __syncthreads();
  const int w = tid >> 6, lane = tid & 63;
  const int lrow = lane & 31, lgrp = lane >> 5;
  const int tk0 = tokLds[lrow];
  const int tk1 = tokLds[32 + lrow];
  const int tk2 = tokLds[64 + lrow];
  const int tk3 = tokLds[96 + lrow];
  __syncthreads();   // all token reads done before red is overwritten

  f32x16 acc[4];
#pragma unroll
  for (int mf = 0; mf < 4; ++mf)
#pragma unroll
    for (int r = 0; r < 16; ++r) acc[mf][r] = 0.0f;
  run_phase_p<2>(acc, emb, nullptr, nullptr, nullptr, 0, tk0, tk1, tk2, tk3,
                 PHih0, PMih0, E_, jb, w, lane, lrow, lgrp);
  reduce_waves(red, acc, tid);
  gates_epilogue(red, jb, tid, bih0, bhh0, G0, c0, hOutHi, hOutLo);
}

// final token (t=63) -> out[:, 127]
__global__ void decode_tokens(const u64* __restrict__ winPart,
                              int* __restrict__ out) {
  __shared__ u64 sv[256];
  const int b = blockIdx.x, tid = threadIdx.x;
  u64 m = 0;
  for (int j = tid; j < 250; j += 256) {
    u64 k2 = winPart[(size_t)b * 250 + j];
    if (k2 > m) m = k2;
  }
  sv[tid] = m;
  __syncthreads();
  for (int s = 128; s > 0; s >>= 1) {
    if (tid < s) { if (sv[tid + s] > sv[tid]) sv[tid] = sv[tid + s]; }
    __syncthreads();
  }
  if (tid == 0) out[b * S_ + (S_ - 1)] = (int)(~(uint32_t)(sv[0] & 0xFFFFFFFFull));
}

// ---------------------------------------------------------------------------
extern "C" void kernel_launch(void* const* d_in, const int* in_sizes, int n_in,
                              void* d_out, int out_size, void* d_ws, size_t ws_size,
                              hipStream_t stream) {
  const int*   x    = (const int*)  d_in[0];
  const float* emb  = (const float*)d_in[3];
  const float* Wih0 = (const float*)d_in[4];
  const float* Whh0 = (const float*)d_in[5];
  const float* bih0 = (const float*)d_in[6];
  const float* bhh0 = (const float*)d_in[7];
  const float* Wih1 = (const float*)d_in[8];
  const float* Whh1 = (const float*)d_in[9];
  const float* bih1 = (const float*)d_in[10];
  const float* bhh1 = (const float*)d_in[11];
  const float* Wlin = (const float*)d_in[12];
  const float* blin = (const float*)d_in[13];
  int* out = (int*)d_out;

  // ---- workspace carve-up (~232 MB; r10-r13 proved this fits) ----
  char* wp = (char*)d_ws;
  size_t o = 0;
  auto alloc = [&](size_t bytes) {
    void* p = wp + o; o += (bytes + 255) & ~(size_t)255; return p;
  };
  uint32_t* keys = (uint32_t*)alloc(512);
  float*    c0   = (float*)   alloc((size_t)B_ * H_ * 4);   // zero-block start
  float*    c1   = (float*)   alloc((size_t)B_ * H_ * 4);
  uint16_t* hS0hi[2]; uint16_t* hS0lo[2]; uint16_t* hS1hi[2]; uint16_t* hS1lo[2];
  for (int i = 0; i < 2; ++i) hS0hi[i] = (uint16_t*)alloc((size_t)B_ * H_ * 2);
  for (int i = 0; i < 2; ++i) hS0lo[i] = (uint16_t*)alloc((size_t)B_ * H_ * 2);
  for (int i = 0; i < 2; ++i) hS1hi[i] = (uint16_t*)alloc((size_t)B_ * H_ * 2);
  for (int i = 0; i < 2; ++i) hS1lo[i] = (uint16_t*)alloc((size_t)B_ * H_ * 2);
  size_t zeroBytes = (size_t)((char*)hS1lo[1] + (size_t)B_ * H_ * 2 - (char*)c0);
  float* G0      = (float*)alloc((size_t)B_ * H4_ * 4);          // 4 MB
  u64*   winPart = (u64*)  alloc((size_t)B_ * 250 * 8);          // 256 KB

  const size_t nIh0 = (size_t)H4_ * E_;
  const size_t nHh  = (size_t)H4_ * H_;
  const size_t nLin = (size_t)V_ * H_;
  uint16_t* PHih0 = (uint16_t*)alloc(nIh0 * 2);
  uint8_t*  PMih0 = (uint8_t*) alloc(nIh0);
  uint16_t* PHhh0 = (uint16_t*)alloc(nHh * 2);
  uint8_t*  PMhh0 = (uint8_t*) alloc(nHh);
  uint16_t* PHih1 = (uint16_t*)alloc(nHh * 2);
  uint8_t*  PMih1 = (uint8_t*) alloc(nHh);
  uint16_t* PHhh1 = (uint16_t*)alloc(nHh * 2);
  uint8_t*  PMhh1 = (uint8_t*) alloc(nHh);
  uint16_t* PHlin = (uint16_t*)alloc(nLin * 2);
  uint8_t*  PMlin = (uint8_t*) alloc(nLin);

  hipMemsetAsync(c0, 0, zeroBytes, stream);
  keys_kernel<<<1, 64, 0, stream>>>(keys);
  copy_prefix<<<(B_ * GIVEN_) / 256, 256, 0, stream>>>(x, out);
  pack3_panel<<<256 * 32,  64, 0, stream>>>(Wih0, PHih0, PMih0, E_, 32, 1);
  pack3_panel<<<256 * 128, 64, 0, stream>>>(Whh0, PHhh0, PMhh0, H_, 128, 1);
  pack3_panel<<<256 * 128, 64, 0, stream>>>(Wih1, PHih1, PMih1, H_, 128, 1);
  pack3_panel<<<256 * 128, 64, 0, stream>>>(Whh1, PHhh1, PMhh1, H_, 128, 1);
  pack3_panel<<<250 * 128, 64, 0, stream>>>(Wlin, PHlin, PMlin, H_, 128, 0);

  int cur0 = 0, cur1 = 0;
  auto mkL0 = [&](const int* ridx) {
    LayerArgs A;
    A.aF = emb; A.ridx = ridx; A.rstride = S_;
    A.a1Hi = nullptr; A.a1Lo = nullptr;
    A.PH1 = PHih0; A.PM1 = PMih0; A.K1 = E_;
    A.a2Hi = hS0hi[cur0]; A.a2Lo = hS0lo[cur0];
    A.PH2 = PHhh0; A.PM2 = PMhh0; A.K2 = H_;
    A.bih = bih0; A.bhh = bhh0; A.cS = c0;
    A.hOutHi = hS0hi[cur0 ^ 1]; A.hOutLo = hS0lo[cur0 ^ 1];
    return A;
  };
  auto mkL1 = [&]() {
    LayerArgs A;
    A.aF = nullptr; A.ridx = nullptr; A.rstride = 0;
    A.a1Hi = hS0hi[cur0]; A.a1Lo = hS0lo[cur0];
    A.PH1 = PHih1; A.PM1 = PMih1; A.K1 = H_;
    A.a2Hi = hS1hi[cur1]; A.a2Lo = hS1lo[cur1];
    A.PH2 = PHhh1; A.PM2 = PMhh1; A.K2 = H_;
    A.bih = bih1; A.bhh = bhh1; A.cS = c1;
    A.hOutHi = hS1hi[cur1 ^ 1]; A.hOutLo = hS1lo[cur1 ^ 1];
    return A;
  };

  // ---- teacher forcing ----
  lstm_single<1><<<256, 512, 0, stream>>>(mkL0(x + 0));
  cur0 ^= 1;
  for (int t = 1; t < GIVEN_; ++t) {
    fused_tf<<<dim3(256, 2), 512, 0, stream>>>(mkL1(), mkL0(x + t));
    cur0 ^= 1; cur1 ^= 1;
  }
  lstm_single<0><<<256, 512, 0, stream>>>(mkL1());
  cur1 ^= 1;

  // ---- rollout ----
  lstm_single<1><<<256, 512, 0, stream>>>(mkL0(x + (GIVEN_ - 1)));
  cur0 ^= 1;
  for (int t = 0; t < S_ - GIVEN_; ++t) {
    fused_r<<<dim3(256, 2), 512, 0, stream>>>(
        mkL1(), hS0hi[cur0], hS0lo[cur0], PHhh0, PMhh0, G0,
        (t < S_ - GIVEN_ - 1) ? 1 : 0);
    cur1 ^= 1;
    logits_pmax<<<250, 512, 0, stream>>>(
        hS1hi[cur1], hS1lo[cur1], PHlin, PMlin, blin, keys, t, winPart);
    if (t < S_ - GIVEN_ - 1) {
      l0_finish<<<256, 512, 0, stream>>>(
          winPart, emb, PHih0, PMih0, G0, bih0, bhh0, c0,
          hS0hi[cur0 ^ 1], hS0lo[cur0 ^ 1], out, GIVEN_ + t);
      cur0 ^= 1;
    }
  }
  decode_tokens<<<128, 256, 0, stream>>>(winPart, out);
}